// Round 5
// baseline (295.303 us; speedup 1.0000x reference)
//
#include <hip/hip_runtime.h>
#include <hip/hip_bf16.h>

typedef __bf16 bf16x8 __attribute__((ext_vector_type(8)));
typedef __bf16 bf16x4 __attribute__((ext_vector_type(4)));
typedef float  f32x4  __attribute__((ext_vector_type(4)));

namespace {
constexpr int P       = 20001;   // MOVIES + 1 (padding row)
constexpr int NT_TILE = 1251;    // ceil(P/16) -> covers movies 0..20015
constexpr int PROWS   = NT_TILE * 16;  // 20016 padded rows for T/GT/ACC
constexpr int NGENRES = 20;
constexpr int NTAGS   = 1000;
constexpr int NGTAGS  = 1128;
constexpr int NB      = 1024;
constexpr int NH      = 50;
constexpr int PHID    = 256;
constexpr int OD      = 128;
constexpr int EG = 8, ET = 16, EGT = 16, EM = 32, EY = 8, EUG = 32, ETS = 4;
constexpr int PAD  = 20000;
constexpr int SC   = 104;    // s_cat stride bf16 (96 used)
constexpr int SH   = 264;    // hidden stride bf16 (256 used)
constexpr int UC   = 192;    // user-cat padded width (180 + 12 zeros)
constexpr int UCS  = 200;    // mlp LDS stride for Ucat tile
// fragment-table chunk counts (chunks of K=32 -> one [64][8] bf16 frag = 1KB)
constexpr int KC_TAG  = 32;
constexpr int KC_GENF = 40;  // genome frags padded 36->40 (zeros) for uniform slices
constexpr int KC_IP1 = 3,  NT_IP1 = 16;   // K=96(80 real), N=256
constexpr int KC_IP2 = 8,  NT_IP2 = 8;    // K=256, N=128
constexpr int KC_UP1 = 6,  NT_UP1 = 16;   // K=192(180 real), N=256
constexpr int KC_UP2 = 8,  NT_UP2 = 8;    // K=256, N=128
}

static __device__ __forceinline__ f32x4 mfma16(bf16x8 a, bf16x8 b, f32x4 c) {
  return __builtin_amdgcn_mfma_f32_16x16x32_bf16(a, b, c, 0, 0, 0);
}

static __device__ __forceinline__ bf16x8 cvt8(float4 v0, float4 v1) {
  return (bf16x8){(__bf16)v0.x, (__bf16)v0.y, (__bf16)v0.z, (__bf16)v0.w,
                  (__bf16)v1.x, (__bf16)v1.y, (__bf16)v1.z, (__bf16)v1.w};
}

// ---------------------------------------------------------------------------
// Setup: pre-swizzle all MFMA B-operands into fragment layout:
// frag(kc, nt)[lane][j] = W[kc*32 + (lane>>4)*8 + j][nt*16 + (lane&15)] (bf16,
// zero past K). One block (512 thr) per fragment; 344 fragments total.
// Genome gets 40 frags (36 real + 4 zero) so stream slices are uniform.
// ---------------------------------------------------------------------------
__global__ __launch_bounds__(512) void setup_wf_kernel(
    const float* __restrict__ w_tag, const float* __restrict__ w_genome,
    const float* __restrict__ w_ip1, const float* __restrict__ w_ip2,
    const float* __restrict__ w_up1, const float* __restrict__ w_up2,
    __bf16* __restrict__ Wtf, __bf16* __restrict__ Wgf,
    __bf16* __restrict__ Wip1f, __bf16* __restrict__ Wip2f,
    __bf16* __restrict__ Wup1f, __bf16* __restrict__ Wup2f)
{
  const int b = blockIdx.x, t = threadIdx.x;
  const int l = t >> 3, j = t & 7;
  const int krow = (l >> 4) * 8 + j, l15 = l & 15;
  const float* src; __bf16* dst; int K, N, kc, nt;
  if (b < 32)        { src = w_tag;    dst = Wtf   + (long)b * 512;       K = NTAGS;  N = 16;  kc = b;      nt = 0; }
  else if (b < 72)   { int i = b - 32;  src = w_genome; dst = Wgf   + (long)i * 512; K = NGTAGS; N = 16;  kc = i;      nt = 0; }
  else if (b < 120)  { int i = b - 72;  src = w_ip1;    dst = Wip1f + (long)i * 512; K = 80;     N = 256; kc = i / 16; nt = i % 16; }
  else if (b < 184)  { int i = b - 120; src = w_ip2;    dst = Wip2f + (long)i * 512; K = 256;    N = 128; kc = i / 8;  nt = i % 8; }
  else if (b < 280)  { int i = b - 184; src = w_up1;    dst = Wup1f + (long)i * 512; K = 180;    N = 256; kc = i / 16; nt = i % 16; }
  else               { int i = b - 280; src = w_up2;    dst = Wup2f + (long)i * 512; K = 256;    N = 128; kc = i / 8;  nt = i % 8; }
  const int k = kc * 32 + krow, n = nt * 16 + l15;
  float v = (k < K) ? src[(long)k * N + n] : 0.f;
  dst[t] = (__bf16)v;
}

// ---------------------------------------------------------------------------
// Stream: PURE tag+genome GEMM, phase-isolated for attribution.
// grid (1251, 4) x 128 thr: each WAVE is an independent (tile, K-slice) work
// item -- 10008 independent waves, ~20-24/CU resident, no LDS, no barriers.
// Wave s of tile: tag kcg s*4+{0..3}, genome kcg s*5+{0..4} (frags 36..39 are
// zero). All 18 A-loads issued in one fenced batch (18KB/wave in flight).
// Partial sums accumulate via atomicAdd into ACC[20016][32] fp32
// (cols 0..15 tag pre-bias, 16..31 genome pre-bias); ACC memset per launch.
// ---------------------------------------------------------------------------
__global__ __launch_bounds__(128, 5) void stream_kernel(
    const float* __restrict__ tag_ctx, const float* __restrict__ genome_ctx,
    const __bf16* __restrict__ Wtf, const __bf16* __restrict__ Wgf,
    float* __restrict__ ACC)
{
  const int t = threadIdx.x, tile = blockIdx.x;
  const int wave = t >> 6, lane = t & 63, l15 = lane & 15, quad = lane >> 4;
  const int s = blockIdx.y * 2 + wave;              // K-slice 0..7
  const long rid = min(tile * 16 + l15, P - 1);
  const float* trow = tag_ctx    + rid * NTAGS;
  const float* grow = genome_ctx + rid * NGTAGS;

  // ---- one fenced batch: 8 tag + 10 genome dwordx4 (72 VGPR in flight) ----
  float4 ta[8], ga[10];
  #pragma unroll
  for (int c = 0; c < 4; ++c) {
    const int cc = min((s * 4 + c) * 32 + quad * 8, NTAGS - 8);
    ta[2 * c]     = *(const float4*)(trow + cc);
    ta[2 * c + 1] = *(const float4*)(trow + cc + 4);
  }
  #pragma unroll
  for (int c = 0; c < 5; ++c) {
    const int cc = min((s * 5 + c) * 32 + quad * 8, NGTAGS - 8);
    ga[2 * c]     = *(const float4*)(grow + cc);
    ga[2 * c + 1] = *(const float4*)(grow + cc + 4);
  }
  __builtin_amdgcn_sched_barrier(0);   // loads may not sink below this point

  f32x4 accT = {0.f, 0.f, 0.f, 0.f};
  #pragma unroll
  for (int c = 0; c < 4; ++c) {
    bf16x8 tb = *(const bf16x8*)(Wtf + ((long)(s * 4 + c) * 64 + lane) * 8);
    accT = mfma16(cvt8(ta[2 * c], ta[2 * c + 1]), tb, accT);
  }
  f32x4 accG = {0.f, 0.f, 0.f, 0.f};
  #pragma unroll
  for (int c = 0; c < 5; ++c) {
    bf16x8 gb = *(const bf16x8*)(Wgf + ((long)(s * 5 + c) * 64 + lane) * 8);
    accG = mfma16(cvt8(ga[2 * c], ga[2 * c + 1]), gb, accG);
  }

  // C-layout: col = lane&15, row = quad*4 + reg
  float* arow = ACC + (long)(tile * 16 + quad * 4) * 32;
  #pragma unroll
  for (int r2 = 0; r2 < 4; ++r2) {
    atomicAdd(arow + (long)r2 * 32 + l15,      accT[r2]);
    atomicAdd(arow + (long)r2 * 32 + 16 + l15, accG[r2]);
  }
}

// ---------------------------------------------------------------------------
// Item MLP: bias+tanh on ACC, small towers, ip1, ip2 -> T, GT.
// One block = one 16-movie tile. Phase-isolated from the stream.
// ---------------------------------------------------------------------------
__global__ __launch_bounds__(256) void item_mlp_kernel(
    const float* __restrict__ genre_ctx, const int* __restrict__ year_ctx,
    const float* __restrict__ item_emb, const float* __restrict__ year_tab,
    const float* __restrict__ w_genre, const float* __restrict__ b_genre,
    const float* __restrict__ b_tag,   const float* __restrict__ b_genome,
    const float* __restrict__ w_item,  const float* __restrict__ b_item,
    const float* __restrict__ w_year,  const float* __restrict__ b_year,
    const float* __restrict__ b_ip1,   const float* __restrict__ b_ip2,
    const __bf16* __restrict__ Wip1f, const __bf16* __restrict__ Wip2f,
    const float* __restrict__ ACC,
    float* __restrict__ T, float* __restrict__ GT)
{
  __shared__ __align__(16) __bf16 s_cat[16][SC];   // 3.3 KB
  __shared__ __align__(16) __bf16 s_h[16][SH];     // 8.4 KB

  const int t = threadIdx.x, tile = blockIdx.x;
  const int wave = t >> 6, lane = t & 63, l15 = lane & 15, quad = lane >> 4;
  const int r = t >> 4, c16 = t & 15;
  const long rid_r = min(tile * 16 + r, P - 1);

  // ---- stage ACC -> bias -> tanh -> s_cat[:,8..40); genome also -> GT ----
  if (t < 128) {
    const int m = t >> 3, c4 = t & 7;
    const long row = (long)tile * 16 + m;
    float4 v = *(const float4*)(ACC + row * 32 + c4 * 4);
    const float vv[4] = {v.x, v.y, v.z, v.w};
    #pragma unroll
    for (int j = 0; j < 4; ++j) {
      const int c = c4 * 4 + j;
      const float bias = (c < 16) ? b_tag[c] : b_genome[c - 16];
      const float val = tanhf(vv[j] + bias);
      s_cat[m][8 + c] = (__bf16)val;
      if (c >= 16) GT[row * EGT + (c - 16)] = val;
    }
  }

  // ---- small towers: 16 threads per movie (m = t>>4, j = t&15) ----
  {
    const int m = r, j = c16;
    const long id = rid_r;
    if (j < 8) {   // genre tower (8 cols)
      const float* rg = genre_ctx + id * NGENRES;
      float a = b_genre[j];
      #pragma unroll
      for (int k = 0; k < NGENRES; ++k) a = fmaf(rg[k], w_genre[k * EG + j], a);
      s_cat[m][j] = (__bf16)tanhf(a);
      s_cat[m][80 + j] = (__bf16)0.f;          // zero K-pad 80..95
      s_cat[m][88 + j] = (__bf16)0.f;
    } else {       // year tower (8 cols)
      const int jj = j - 8;
      const int yr = year_ctx[id];
      float a = b_year[jj];
      #pragma unroll
      for (int k = 0; k < EY; ++k)
        a = fmaf(year_tab[yr * EY + k], w_year[k * EY + jj], a);
      s_cat[m][72 + jj] = (__bf16)tanhf(a);    // 72 = EG+ET+EGT+EM
    }
    // item tower: every thread 2 cols
    const float* e = item_emb + id * EM;
    float a0 = b_item[2 * j], a1 = b_item[2 * j + 1];
    #pragma unroll 8
    for (int k = 0; k < EM; ++k) {
      float ev = e[k];
      a0 = fmaf(ev, w_item[k * EM + 2 * j], a0);
      a1 = fmaf(ev, w_item[k * EM + 2 * j + 1], a1);
    }
    s_cat[m][40 + 2 * j]     = (__bf16)tanhf(a0);   // 40 = EG+ET+EGT
    s_cat[m][40 + 2 * j + 1] = (__bf16)tanhf(a1);
  }
  __syncthreads();

  // ===== ip1 MFMA [16,96]@[96,256] -> relu -> s_h =====
  {
    bf16x8 af[KC_IP1];
    #pragma unroll
    for (int kc = 0; kc < KC_IP1; ++kc)
      af[kc] = *(const bf16x8*)&s_cat[l15][kc * 32 + quad * 8];
    #pragma unroll
    for (int nt = 0; nt < 4; ++nt) {
      const int n = wave * 64 + nt * 16 + l15;
      const float bb = b_ip1[n];
      f32x4 acc = {bb, bb, bb, bb};
      bf16x8 bfr[KC_IP1];
      #pragma unroll
      for (int kc = 0; kc < KC_IP1; ++kc)
        bfr[kc] = *(const bf16x8*)(Wip1f + ((long)(kc * NT_IP1 + wave * 4 + nt) * 64 + lane) * 8);
      #pragma unroll
      for (int kc = 0; kc < KC_IP1; ++kc)
        acc = mfma16(af[kc], bfr[kc], acc);
      #pragma unroll
      for (int r2 = 0; r2 < 4; ++r2)
        s_h[quad * 4 + r2][n] = (__bf16)fmaxf(acc[r2], 0.f);
    }
  }
  __syncthreads();

  // ===== ip2 MFMA [16,256]@[256,128] -> T =====
  {
    bf16x8 af[KC_IP2];
    #pragma unroll
    for (int kc = 0; kc < KC_IP2; ++kc)
      af[kc] = *(const bf16x8*)&s_h[l15][kc * 32 + quad * 8];
    #pragma unroll
    for (int nt = 0; nt < 2; ++nt) {
      const int n = wave * 32 + nt * 16 + l15;
      const float bb = b_ip2[n];
      f32x4 acc = {bb, bb, bb, bb};
      bf16x8 bfr[KC_IP2];
      #pragma unroll
      for (int kc = 0; kc < KC_IP2; ++kc)
        bfr[kc] = *(const bf16x8*)(Wip2f + ((long)(kc * NT_IP2 + wave * 2 + nt) * 64 + lane) * 8);
      #pragma unroll
      for (int kc = 0; kc < KC_IP2; ++kc)
        acc = mfma16(af[kc], bfr[kc], acc);
      #pragma unroll
      for (int r2 = 0; r2 < 4; ++r2)
        T[(long)(tile * 16 + quad * 4 + r2) * OD + n] = acc[r2];
    }
  }
}

// ---------------------------------------------------------------------------
// Pool: per-user pooling -> Ucat[1024][192] bf16 (180 real + 12 zeros).
// ---------------------------------------------------------------------------
__global__ __launch_bounds__(256) void user_pool_kernel(
    const float* __restrict__ ugc, const int* __restrict__ hist,
    const float* __restrict__ ratings, const int* __restrict__ tstamps,
    const float* __restrict__ ts_tab,
    const float* __restrict__ w_ugenre, const float* __restrict__ b_ugenre,
    const float* __restrict__ w_ts, const float* __restrict__ b_ts,
    const float* __restrict__ T, const float* __restrict__ GT,
    __bf16* __restrict__ Ucat)
{
  __shared__ float s_w[64];
  __shared__ int   s_ids[64];
  __shared__ float s_part[2][OD];
  __shared__ float s_gp[8][EGT];
  __shared__ float s_inv;

  const int b = blockIdx.x, t = threadIdx.x;

  if (t < 64) {
    int id = PAD; float w = 0.f;
    if (t < NH) {
      id = hist[b * NH + t];
      float r = ratings[b * NH + t];
      w = (id != PAD) ? r : 0.f;
    }
    s_ids[t] = id; s_w[t] = w;
    float s = fabsf(w);
    #pragma unroll
    for (int off = 32; off; off >>= 1) s += __shfl_xor(s, off, 64);
    if (t == 0) s_inv = 1.f / fmaxf(s, 1e-6f);
  }
  __syncthreads();
  const float inv = s_inv;

  {  // item pool partials: 2 x 25 gathers per column (256B contig per wave)
    const int c = t & (OD - 1), part = t >> 7;
    float acc = 0.f;
    #pragma unroll
    for (int i = 0; i < 25; ++i) {
      const int h = part * 25 + i;
      acc = fmaf(s_w[h], T[(long)s_ids[h] * OD + c], acc);
    }
    s_part[part][c] = acc;
  }
  __syncthreads();
  if (t < OD) {
    Ucat[(long)b * UC + t] = (__bf16)((s_part[0][t] + s_part[1][t]) * inv);
  } else {
    const int uu = t - 128, col = uu & 15, part = uu >> 4;  // 8 parts x 7 h
    float acc = 0.f;
    #pragma unroll
    for (int i = 0; i < 7; ++i) {
      const int h = part * 7 + i;
      if (h < NH) acc = fmaf(s_w[h], GT[(long)s_ids[h] * EGT + col], acc);
    }
    s_gp[part][col] = acc;
  }
  __syncthreads();
  if (t < EGT) {
    float acc = 0.f;
    #pragma unroll
    for (int p = 0; p < 8; ++p) acc += s_gp[p][t];
    Ucat[(long)b * UC + OD + t] = (__bf16)(acc * inv);
  } else if (t >= 32 && t < 64) {
    const int j = t - 32;
    float a = b_ugenre[j];
    #pragma unroll
    for (int k = 0; k < NGENRES; ++k)
      a = fmaf(ugc[b * NGENRES + k], w_ugenre[k * EUG + j], a);
    Ucat[(long)b * UC + 144 + j] = (__bf16)tanhf(a);     // 128+16
  } else if (t >= 64 && t < 64 + ETS) {
    const int j = t - 64;
    const int ts = tstamps[b];
    float a = b_ts[j];
    #pragma unroll
    for (int k = 0; k < ETS; ++k)
      a = fmaf(ts_tab[ts * ETS + k], w_ts[k * ETS + j], a);
    Ucat[(long)b * UC + 176 + j] = (__bf16)tanhf(a);     // 128+16+32
  } else if (t >= 68 && t < 80) {
    Ucat[(long)b * UC + 180 + (t - 68)] = (__bf16)0.f;   // zero pad
  }
}

// ---------------------------------------------------------------------------
// MLP: user MLP via MFMA + final dot. 64 blocks x 16 users; weights from
// pre-swizzled frag tables (coalesced, L2-hot).
// ---------------------------------------------------------------------------
__global__ __launch_bounds__(256) void user_mlp_kernel(
    const int* __restrict__ target,
    const float* __restrict__ b_up1, const float* __restrict__ b_up2,
    const __bf16* __restrict__ Wup1f, const __bf16* __restrict__ Wup2f,
    const __bf16* __restrict__ Ucat, const float* __restrict__ T,
    float* __restrict__ out)
{
  __shared__ __align__(16) __bf16 s_u[16][UCS];   // 6.4 KB
  __shared__ __align__(16) __bf16 s_h[16][SH];    // 8.4 KB
  __shared__ __align__(16) float  s_e[16][132];   // 8.4 KB

  const int t = threadIdx.x, blk = blockIdx.x;
  const int wave = t >> 6, lane = t & 63, l15 = lane & 15, quad = lane >> 4;
  const int u0 = blk * 16;

  {  // stage Ucat tile: 16 thr/user, segs of 8 bf16 (24 segs of 16B)
    const int uu = t >> 4, s = t & 15;
    const __bf16* src = Ucat + (long)(u0 + uu) * UC;
    *(bf16x8*)&s_u[uu][s * 8] = *(const bf16x8*)(src + s * 8);
    if (s < 8)
      *(bf16x8*)&s_u[uu][(s + 16) * 8] = *(const bf16x8*)(src + (s + 16) * 8);
  }
  __syncthreads();

  // ---- up1: [16,192]@[192,256] -> relu -> s_h ----
  {
    bf16x8 af[KC_UP1];
    #pragma unroll
    for (int kc = 0; kc < KC_UP1; ++kc)
      af[kc] = *(const bf16x8*)&s_u[l15][kc * 32 + quad * 8];
    #pragma unroll
    for (int nt = 0; nt < 4; ++nt) {
      const int n = wave * 64 + nt * 16 + l15;
      const float bb = b_up1[n];
      f32x4 acc = {bb, bb, bb, bb};
      bf16x8 bfr[KC_UP1];
      #pragma unroll
      for (int kc = 0; kc < KC_UP1; ++kc)
        bfr[kc] = *(const bf16x8*)(Wup1f + ((long)(kc * NT_UP1 + wave * 4 + nt) * 64 + lane) * 8);
      #pragma unroll
      for (int kc = 0; kc < KC_UP1; ++kc)
        acc = mfma16(af[kc], bfr[kc], acc);
      #pragma unroll
      for (int r2 = 0; r2 < 4; ++r2)
        s_h[quad * 4 + r2][n] = (__bf16)fmaxf(acc[r2], 0.f);
    }
  }
  __syncthreads();

  // ---- up2: [16,256]@[256,128] -> s_e fp32 ----
  {
    bf16x8 af[KC_UP2];
    #pragma unroll
    for (int kc = 0; kc < KC_UP2; ++kc)
      af[kc] = *(const bf16x8*)&s_h[l15][kc * 32 + quad * 8];
    #pragma unroll
    for (int nt = 0; nt < 2; ++nt) {
      const int n = wave * 32 + nt * 16 + l15;
      const float bb = b_up2[n];
      f32x4 acc = {bb, bb, bb, bb};
      bf16x8 bfr[KC_UP2];
      #pragma unroll
      for (int kc = 0; kc < KC_UP2; ++kc)
        bfr[kc] = *(const bf16x8*)(Wup2f + ((long)(kc * NT_UP2 + wave * 2 + nt) * 64 + lane) * 8);
      #pragma unroll
      for (int kc = 0; kc < KC_UP2; ++kc)
        acc = mfma16(af[kc], bfr[kc], acc);
      #pragma unroll
      for (int r2 = 0; r2 < 4; ++r2)
        s_e[quad * 4 + r2][n] = acc[r2];
    }
  }
  __syncthreads();

  // ---- dot(user, T[target]): 8 threads per user ----
  if (t < 128) {
    const int uu = t >> 3, q = t & 7;
    const int tgt = target[u0 + uu];
    const float* trow = T + (long)tgt * OD + q * 16;
    float s = 0.f;
    #pragma unroll
    for (int i = 0; i < 4; ++i) {
      float4 v = *(const float4*)(trow + i * 4);
      f32x4 e = *(const f32x4*)&s_e[uu][q * 16 + i * 4];
      s += v.x * e[0] + v.y * e[1] + v.z * e[2] + v.w * e[3];
    }
    s += __shfl_down(s, 1, 64);
    s += __shfl_down(s, 2, 64);
    s += __shfl_down(s, 4, 64);
    if (q == 0) out[u0 + uu] = s;
  }
}

// ---------------------------------------------------------------------------
extern "C" void kernel_launch(void* const* d_in, const int* in_sizes, int n_in,
                              void* d_out, int out_size, void* d_ws, size_t ws_size,
                              hipStream_t stream) {
  const float* ugc      = (const float*)d_in[0];
  const int*   hist     = (const int*)  d_in[1];
  const float* ratings  = (const float*)d_in[2];
  const int*   tstamps  = (const int*)  d_in[3];
  const int*   target   = (const int*)  d_in[4];
  const float* genome   = (const float*)d_in[5];
  const float* genrec   = (const float*)d_in[6];
  const float* tagc     = (const float*)d_in[7];
  const int*   yearc    = (const int*)  d_in[8];
  const float* item_emb = (const float*)d_in[9];
  const float* year_tab = (const float*)d_in[10];
  const float* ts_tab   = (const float*)d_in[11];
  const float* w_item   = (const float*)d_in[12];
  const float* b_item   = (const float*)d_in[13];
  const float* w_genre  = (const float*)d_in[14];
  const float* b_genre  = (const float*)d_in[15];
  const float* w_tag    = (const float*)d_in[16];
  const float* b_tag    = (const float*)d_in[17];
  const float* w_genome = (const float*)d_in[18];
  const float* b_genome = (const float*)d_in[19];
  const float* w_year   = (const float*)d_in[20];
  const float* b_year   = (const float*)d_in[21];
  const float* w_ugenre = (const float*)d_in[22];
  const float* b_ugenre = (const float*)d_in[23];
  const float* w_ts     = (const float*)d_in[24];
  const float* b_ts     = (const float*)d_in[25];
  const float* w_up1    = (const float*)d_in[26];
  const float* b_up1    = (const float*)d_in[27];
  const float* w_up2    = (const float*)d_in[28];
  const float* b_up2    = (const float*)d_in[29];
  const float* w_ip1    = (const float*)d_in[30];
  const float* b_ip1    = (const float*)d_in[31];
  const float* w_ip2    = (const float*)d_in[32];
  const float* b_ip2    = (const float*)d_in[33];

  char* ws = (char*)d_ws;
  size_t off = 0;
  float*  T     = (float*) (ws + off); off += (size_t)PROWS * OD * 4;     // 10.25 MB
  float*  GT    = (float*) (ws + off); off += (size_t)PROWS * EGT * 4;    // 1.28 MB
  float*  ACC   = (float*) (ws + off); off += (size_t)PROWS * 32 * 4;     // 2.56 MB
  __bf16* Ucat  = (__bf16*)(ws + off); off += (size_t)NB * UC * 2;        // 0.39 MB
  __bf16* Wtf   = (__bf16*)(ws + off); off += (size_t)KC_TAG  * 512 * 2;
  __bf16* Wgf   = (__bf16*)(ws + off); off += (size_t)KC_GENF * 512 * 2;
  __bf16* Wip1f = (__bf16*)(ws + off); off += (size_t)KC_IP1 * NT_IP1 * 512 * 2;
  __bf16* Wip2f = (__bf16*)(ws + off); off += (size_t)KC_IP2 * NT_IP2 * 512 * 2;
  __bf16* Wup1f = (__bf16*)(ws + off); off += (size_t)KC_UP1 * NT_UP1 * 512 * 2;
  __bf16* Wup2f = (__bf16*)(ws + off); off += (size_t)KC_UP2 * NT_UP2 * 512 * 2;

  hipMemsetAsync(ACC, 0, (size_t)PROWS * 32 * 4, stream);

  setup_wf_kernel<<<dim3(344), dim3(512), 0, stream>>>(
      w_tag, w_genome, w_ip1, w_ip2, w_up1, w_up2,
      Wtf, Wgf, Wip1f, Wip2f, Wup1f, Wup2f);

  stream_kernel<<<dim3(NT_TILE, 4), dim3(128), 0, stream>>>(
      tagc, genome, Wtf, Wgf, ACC);

  item_mlp_kernel<<<dim3(NT_TILE), dim3(256), 0, stream>>>(
      genrec, yearc, item_emb, year_tab,
      w_genre, b_genre, b_tag, b_genome, w_item, b_item, w_year, b_year,
      b_ip1, b_ip2, Wip1f, Wip2f, ACC, T, GT);

  user_pool_kernel<<<dim3(NB), dim3(256), 0, stream>>>(
      ugc, hist, ratings, tstamps, ts_tab,
      w_ugenre, b_ugenre, w_ts, b_ts, T, GT, Ucat);

  user_mlp_kernel<<<dim3(NB / 16), dim3(256), 0, stream>>>(
      target, b_up1, b_up2, Wup1f, Wup2f, Ucat, T, (float*)d_out);
}

// Round 6
// 284.705 us; speedup vs baseline: 1.0372x; 1.0372x over previous
//
#include <hip/hip_runtime.h>
#include <hip/hip_bf16.h>

typedef __bf16 bf16x8 __attribute__((ext_vector_type(8)));
typedef __bf16 bf16x4 __attribute__((ext_vector_type(4)));
typedef float  f32x4  __attribute__((ext_vector_type(4)));

namespace {
constexpr int P       = 20001;   // MOVIES + 1 (padding row)
constexpr int NT_TILE = 1251;    // ceil(P/16) -> covers movies 0..20015
constexpr int PROWS   = NT_TILE * 16;  // 20016 padded rows for T/GT
constexpr int NGENRES = 20;
constexpr int NTAGS   = 1000;
constexpr int NGTAGS  = 1128;
constexpr int NB      = 1024;
constexpr int NH      = 50;
constexpr int PHID    = 256;
constexpr int OD      = 128;
constexpr int EG = 8, ET = 16, EGT = 16, EM = 32, EY = 8, EUG = 32, ETS = 4;
constexpr int PAD  = 20000;
constexpr int SC   = 104;    // s_cat stride bf16 (96 used)
constexpr int SH   = 264;    // hidden stride bf16 (256 used)
constexpr int UC   = 192;    // user-cat padded width (180 + 12 zeros)
constexpr int UCS  = 200;    // mlp LDS stride for Ucat tile
// fragment-table chunk counts (chunks of K=32 -> one [64][8] bf16 frag = 1KB)
constexpr int KC_TAG  = 32;
constexpr int KC_GENF = 40;  // genome frags padded 36->40 (zeros): 2 halves x 20
constexpr int KC_IP1 = 3,  NT_IP1 = 16;   // K=96(80 real), N=256
constexpr int KC_IP2 = 8,  NT_IP2 = 8;    // K=256, N=128
constexpr int KC_UP1 = 6,  NT_UP1 = 16;   // K=192(180 real), N=256
constexpr int KC_UP2 = 8,  NT_UP2 = 8;    // K=256, N=128
}

static __device__ __forceinline__ f32x4 mfma16(bf16x8 a, bf16x8 b, f32x4 c) {
  return __builtin_amdgcn_mfma_f32_16x16x32_bf16(a, b, c, 0, 0, 0);
}

static __device__ __forceinline__ bf16x8 cvt8(float4 v0, float4 v1) {
  return (bf16x8){(__bf16)v0.x, (__bf16)v0.y, (__bf16)v0.z, (__bf16)v0.w,
                  (__bf16)v1.x, (__bf16)v1.y, (__bf16)v1.z, (__bf16)v1.w};
}

// async global->LDS DMA, 16B per lane, dest = wave-uniform base + lane*16
static __device__ __forceinline__ void gldlds(const void* g, void* l) {
  __builtin_amdgcn_global_load_lds(
      (const __attribute__((address_space(1))) void*)g,
      (__attribute__((address_space(3))) void*)l, 16, 0, 0);
}

// ---------------------------------------------------------------------------
// Setup: pre-swizzle all MFMA B-operands into fragment layout:
// frag(kc, nt)[lane][j] = W[kc*32 + (lane>>4)*8 + j][nt*16 + (lane&15)] (bf16,
// zero past K). One block (512 thr) per fragment; 344 fragments total.
// ---------------------------------------------------------------------------
__global__ __launch_bounds__(512) void setup_wf_kernel(
    const float* __restrict__ w_tag, const float* __restrict__ w_genome,
    const float* __restrict__ w_ip1, const float* __restrict__ w_ip2,
    const float* __restrict__ w_up1, const float* __restrict__ w_up2,
    __bf16* __restrict__ Wtf, __bf16* __restrict__ Wgf,
    __bf16* __restrict__ Wip1f, __bf16* __restrict__ Wip2f,
    __bf16* __restrict__ Wup1f, __bf16* __restrict__ Wup2f)
{
  const int b = blockIdx.x, t = threadIdx.x;
  const int l = t >> 3, j = t & 7;
  const int krow = (l >> 4) * 8 + j, l15 = l & 15;
  const float* src; __bf16* dst; int K, N, kc, nt;
  if (b < 32)        { src = w_tag;    dst = Wtf   + (long)b * 512;       K = NTAGS;  N = 16;  kc = b;      nt = 0; }
  else if (b < 72)   { int i = b - 32;  src = w_genome; dst = Wgf   + (long)i * 512; K = NGTAGS; N = 16;  kc = i;      nt = 0; }
  else if (b < 120)  { int i = b - 72;  src = w_ip1;    dst = Wip1f + (long)i * 512; K = 80;     N = 256; kc = i / 16; nt = i % 16; }
  else if (b < 184)  { int i = b - 120; src = w_ip2;    dst = Wip2f + (long)i * 512; K = 256;    N = 128; kc = i / 8;  nt = i % 8; }
  else if (b < 280)  { int i = b - 184; src = w_up1;    dst = Wup1f + (long)i * 512; K = 180;    N = 256; kc = i / 16; nt = i % 16; }
  else               { int i = b - 280; src = w_up2;    dst = Wup2f + (long)i * 512; K = 256;    N = 128; kc = i / 8;  nt = i % 8; }
  const int k = kc * 32 + krow, n = nt * 16 + l15;
  float v = (k < K) ? src[(long)k * N + n] : 0.f;
  dst[t] = (__bf16)v;
}

// ---------------------------------------------------------------------------
// Tower v6: one block = one 16-movie tile, 4 waves.
// KEY CHANGE: staging access PATTERN. All prior versions read 16 rows at the
// SAME column offset simultaneously (row stride 4000/4512B ~ 4KB) -> channel/
// set hotspot, invariant ~2.2 TB/s floor across 6 schedules. Now each 1KB
// global_load_lds instruction reads ONE row's CONTIGUOUS 1KB (row-sequential
// streaming, same shape as the 6.3TB/s copy bench). K processed in halves
// (tag 2x16kc / genome 2x20kc) through a 48KB union buffer; source slots
// XOR-permuted within 128B windows so LDS A-reads avoid the 16-way row-major
// bank conflict (swizzle on GLOBAL source, DMA dest linear -- rule #21).
// Tails: source slot CLAMPED (duplicate finite data x zero B-frags; no NaN).
// ---------------------------------------------------------------------------
__global__ __launch_bounds__(256, 2) void tower_kernel(
    const float* __restrict__ tag_ctx, const float* __restrict__ genome_ctx,
    const float* __restrict__ genre_ctx, const int* __restrict__ year_ctx,
    const float* __restrict__ item_emb, const float* __restrict__ year_tab,
    const float* __restrict__ w_genre, const float* __restrict__ b_genre,
    const float* __restrict__ b_tag,   const float* __restrict__ b_genome,
    const float* __restrict__ w_item,  const float* __restrict__ b_item,
    const float* __restrict__ w_year,  const float* __restrict__ b_year,
    const float* __restrict__ b_ip1,   const float* __restrict__ b_ip2,
    const __bf16* __restrict__ Wtf,   const __bf16* __restrict__ Wgf,
    const __bf16* __restrict__ Wip1f, const __bf16* __restrict__ Wip2f,
    float* __restrict__ T, float* __restrict__ GT)
{
  __shared__ __align__(16) union {
    char tag[16 * 128 * 16];   // 32 KB: [16 rows][128 float4 slots]
    char gen[16 * 192 * 16];   // 48 KB: [16 rows][192 slots] (160 used + pad)
  } u;
  __shared__ __align__(16) __bf16 s_cat[16][SC];   // 3.3 KB
  __shared__ __align__(16) __bf16 s_h[16][SH];     // 8.4 KB
  __shared__ __align__(16) f32x4  s_redT[3][64];   // 3 KB
  __shared__ __align__(16) f32x4  s_redG[3][64];   // 3 KB  -> total ~65.5 KB

  const int t = threadIdx.x, tile = blockIdx.x;
  const int wave = t >> 6, lane = t & 63, l15 = lane & 15, quad = lane >> 4;
  const int r = t >> 4, c16 = t & 15;               // small-tower coords
  const long rid_r = min(tile * 16 + r, P - 1);
  const int x = l15 & 7;                            // read-side XOR key

  f32x4 accT = {0.f, 0.f, 0.f, 0.f};
  f32x4 accG = {0.f, 0.f, 0.f, 0.f};

  // ===== tag: 2 halves of K (16 kc each) ====================================
  #pragma unroll
  for (int h = 0; h < 2; ++h) {
    // stage: wave w -> chunks c=w*8..w*8+7; row rr=c>>1, 1KB chunk i=c&1.
    // LDS slot ls holds global slot (ls^(rr&7)) + h*128, clamped to 249.
    #pragma unroll
    for (int cc = 0; cc < 8; ++cc) {
      const int c = wave * 8 + cc, rr = c >> 1, i = c & 1;
      const long rid = min(tile * 16 + rr, P - 1);
      const char* rp = (const char*)tag_ctx + rid * (NTAGS * 4);
      const int gs = min(((i * 64 + lane) ^ (rr & 7)) + h * 128, 249);
      gldlds(rp + (long)gs * 16, u.tag + ((rr * 128 + i * 64) * 16));
    }
    asm volatile("s_waitcnt vmcnt(0)" ::: "memory");
    __syncthreads();
    #pragma unroll
    for (int c = 0; c < 4; ++c) {                   // K-split: wave w kc w*4+c
      const int kcg = h * 16 + wave * 4 + c;
      const int j = (wave * 4 + c) * 8 + quad * 2;  // low3(j)=quad*2
      const float4* rowp = (const float4*)u.tag + l15 * 128;
      const float4 a0 = rowp[j ^ x];
      const float4 a1 = rowp[(j + 1) ^ x];
      bf16x8 tb = *(const bf16x8*)(Wtf + ((long)kcg * 64 + lane) * 8);
      accT = mfma16(cvt8(a0, a1), tb, accT);
    }
    __syncthreads();                                // before buffer reuse
  }

  // ===== genome: 2 halves of K (20 kc each; frags 36..39 zero) ==============
  #pragma unroll
  for (int h = 0; h < 2; ++h) {
    // stage: wave w -> chunks c=w*12..w*12+11; row rr=c/3, chunk i=c%3.
    #pragma unroll
    for (int cc = 0; cc < 12; ++cc) {
      const int c = wave * 12 + cc, rr = c / 3, i = c % 3;
      const long rid = min(tile * 16 + rr, P - 1);
      const char* rp = (const char*)genome_ctx + rid * (NGTAGS * 4);
      const int gs = min(((i * 64 + lane) ^ (rr & 7)) + h * 160, 281);
      gldlds(rp + (long)gs * 16, u.gen + ((rr * 192 + i * 64) * 16));
    }
    asm volatile("s_waitcnt vmcnt(0)" ::: "memory");
    __syncthreads();
    #pragma unroll
    for (int c = 0; c < 5; ++c) {                   // K-split: wave w kc w*5+c
      const int kcg = h * 20 + wave * 5 + c;
      const int j = (wave * 5 + c) * 8 + quad * 2;  // < 160
      const float4* rowp = (const float4*)u.gen + l15 * 192;
      const float4 a0 = rowp[j ^ x];
      const float4 a1 = rowp[(j + 1) ^ x];
      bf16x8 gb = *(const bf16x8*)(Wgf + ((long)kcg * 64 + lane) * 8);
      accG = mfma16(cvt8(a0, a1), gb, accG);
    }
    __syncthreads();
  }

  if (wave > 0)  s_redT[wave - 1][lane] = accT;
  if (wave != 1) s_redG[wave ? wave - 1 : 0][lane] = accG;  // waves 0,2,3

  // ===== small towers (16 threads per movie: m = t>>4, j = t&15) ============
  {
    const int m = r, j = c16;
    const long id = rid_r;
    if (j < 8) {   // genre tower (8 cols)
      const float* rg = genre_ctx + id * NGENRES;
      float a = b_genre[j];
      #pragma unroll
      for (int k = 0; k < NGENRES; ++k) a = fmaf(rg[k], w_genre[k * EG + j], a);
      s_cat[m][j] = (__bf16)tanhf(a);
      s_cat[m][80 + j] = (__bf16)0.f;          // zero K-pad 80..95
      s_cat[m][88 + j] = (__bf16)0.f;
    } else {       // year tower (8 cols)
      const int jj = j - 8;
      const int yr = year_ctx[id];
      float a = b_year[jj];
      #pragma unroll
      for (int k = 0; k < EY; ++k)
        a = fmaf(year_tab[yr * EY + k], w_year[k * EY + jj], a);
      s_cat[m][72 + jj] = (__bf16)tanhf(a);    // 72 = EG+ET+EGT+EM
    }
    // item tower: every thread 2 cols
    const float* e = item_emb + id * EM;
    float a0 = b_item[2 * j], a1 = b_item[2 * j + 1];
    #pragma unroll 8
    for (int k = 0; k < EM; ++k) {
      float ev = e[k];
      a0 = fmaf(ev, w_item[k * EM + 2 * j], a0);
      a1 = fmaf(ev, w_item[k * EM + 2 * j + 1], a1);
    }
    s_cat[m][40 + 2 * j]     = (__bf16)tanhf(a0);   // 40 = EG+ET+EGT
    s_cat[m][40 + 2 * j + 1] = (__bf16)tanhf(a1);
  }
  __syncthreads();

  // ===== parallel epilogues: wave0 tag, wave1 genome ========================
  if (wave == 0) {
    accT += s_redT[0][lane]; accT += s_redT[1][lane]; accT += s_redT[2][lane];
    const float bt = b_tag[l15];
    #pragma unroll
    for (int r2 = 0; r2 < 4; ++r2)
      s_cat[quad * 4 + r2][EG + l15] = (__bf16)tanhf(accT[r2] + bt);
  } else if (wave == 1) {
    accG += s_redG[0][lane]; accG += s_redG[1][lane]; accG += s_redG[2][lane];
    const float bg = b_genome[l15];
    #pragma unroll
    for (int r2 = 0; r2 < 4; ++r2) {
      int m = quad * 4 + r2;
      float v = tanhf(accG[r2] + bg);
      s_cat[m][EG + ET + l15] = (__bf16)v;
      GT[(long)(tile * 16 + m) * EGT + l15] = v;
    }
  }
  __syncthreads();

  // ===== ip1 MFMA [16,96]@[96,256] -> relu -> s_h =====
  {
    bf16x8 af[KC_IP1];
    #pragma unroll
    for (int kc = 0; kc < KC_IP1; ++kc)
      af[kc] = *(const bf16x8*)&s_cat[l15][kc * 32 + quad * 8];
    #pragma unroll
    for (int nt = 0; nt < 4; ++nt) {
      const int n = wave * 64 + nt * 16 + l15;
      const float bb = b_ip1[n];
      f32x4 acc = {bb, bb, bb, bb};
      bf16x8 bfr[KC_IP1];
      #pragma unroll
      for (int kc = 0; kc < KC_IP1; ++kc)
        bfr[kc] = *(const bf16x8*)(Wip1f + ((long)(kc * NT_IP1 + wave * 4 + nt) * 64 + lane) * 8);
      #pragma unroll
      for (int kc = 0; kc < KC_IP1; ++kc)
        acc = mfma16(af[kc], bfr[kc], acc);
      #pragma unroll
      for (int r2 = 0; r2 < 4; ++r2)
        s_h[quad * 4 + r2][n] = (__bf16)fmaxf(acc[r2], 0.f);
    }
  }
  __syncthreads();

  // ===== ip2 MFMA [16,256]@[256,128] -> T =====
  {
    bf16x8 af[KC_IP2];
    #pragma unroll
    for (int kc = 0; kc < KC_IP2; ++kc)
      af[kc] = *(const bf16x8*)&s_h[l15][kc * 32 + quad * 8];
    #pragma unroll
    for (int nt = 0; nt < 2; ++nt) {
      const int n = wave * 32 + nt * 16 + l15;
      const float bb = b_ip2[n];
      f32x4 acc = {bb, bb, bb, bb};
      bf16x8 bfr[KC_IP2];
      #pragma unroll
      for (int kc = 0; kc < KC_IP2; ++kc)
        bfr[kc] = *(const bf16x8*)(Wip2f + ((long)(kc * NT_IP2 + wave * 2 + nt) * 64 + lane) * 8);
      #pragma unroll
      for (int kc = 0; kc < KC_IP2; ++kc)
        acc = mfma16(af[kc], bfr[kc], acc);
      #pragma unroll
      for (int r2 = 0; r2 < 4; ++r2)
        T[(long)(tile * 16 + quad * 4 + r2) * OD + n] = acc[r2];
    }
  }
}

// ---------------------------------------------------------------------------
// Pool: per-user pooling -> Ucat[1024][192] bf16 (180 real + 12 zeros).
// ---------------------------------------------------------------------------
__global__ __launch_bounds__(256) void user_pool_kernel(
    const float* __restrict__ ugc, const int* __restrict__ hist,
    const float* __restrict__ ratings, const int* __restrict__ tstamps,
    const float* __restrict__ ts_tab,
    const float* __restrict__ w_ugenre, const float* __restrict__ b_ugenre,
    const float* __restrict__ w_ts, const float* __restrict__ b_ts,
    const float* __restrict__ T, const float* __restrict__ GT,
    __bf16* __restrict__ Ucat)
{
  __shared__ float s_w[64];
  __shared__ int   s_ids[64];
  __shared__ float s_part[2][OD];
  __shared__ float s_gp[8][EGT];
  __shared__ float s_inv;

  const int b = blockIdx.x, t = threadIdx.x;

  if (t < 64) {
    int id = PAD; float w = 0.f;
    if (t < NH) {
      id = hist[b * NH + t];
      float r = ratings[b * NH + t];
      w = (id != PAD) ? r : 0.f;
    }
    s_ids[t] = id; s_w[t] = w;
    float s = fabsf(w);
    #pragma unroll
    for (int off = 32; off; off >>= 1) s += __shfl_xor(s, off, 64);
    if (t == 0) s_inv = 1.f / fmaxf(s, 1e-6f);
  }
  __syncthreads();
  const float inv = s_inv;

  {  // item pool partials: 2 x 25 gathers per column (256B contig per wave)
    const int c = t & (OD - 1), part = t >> 7;
    float acc = 0.f;
    #pragma unroll
    for (int i = 0; i < 25; ++i) {
      const int h = part * 25 + i;
      acc = fmaf(s_w[h], T[(long)s_ids[h] * OD + c], acc);
    }
    s_part[part][c] = acc;
  }
  __syncthreads();
  if (t < OD) {
    Ucat[(long)b * UC + t] = (__bf16)((s_part[0][t] + s_part[1][t]) * inv);
  } else {
    const int uu = t - 128, col = uu & 15, part = uu >> 4;  // 8 parts x 7 h
    float acc = 0.f;
    #pragma unroll
    for (int i = 0; i < 7; ++i) {
      const int h = part * 7 + i;
      if (h < NH) acc = fmaf(s_w[h], GT[(long)s_ids[h] * EGT + col], acc);
    }
    s_gp[part][col] = acc;
  }
  __syncthreads();
  if (t < EGT) {
    float acc = 0.f;
    #pragma unroll
    for (int p = 0; p < 8; ++p) acc += s_gp[p][t];
    Ucat[(long)b * UC + OD + t] = (__bf16)(acc * inv);
  } else if (t >= 32 && t < 64) {
    const int j = t - 32;
    float a = b_ugenre[j];
    #pragma unroll
    for (int k = 0; k < NGENRES; ++k)
      a = fmaf(ugc[b * NGENRES + k], w_ugenre[k * EUG + j], a);
    Ucat[(long)b * UC + 144 + j] = (__bf16)tanhf(a);     // 128+16
  } else if (t >= 64 && t < 64 + ETS) {
    const int j = t - 64;
    const int ts = tstamps[b];
    float a = b_ts[j];
    #pragma unroll
    for (int k = 0; k < ETS; ++k)
      a = fmaf(ts_tab[ts * ETS + k], w_ts[k * ETS + j], a);
    Ucat[(long)b * UC + 176 + j] = (__bf16)tanhf(a);     // 128+16+32
  } else if (t >= 68 && t < 80) {
    Ucat[(long)b * UC + 180 + (t - 68)] = (__bf16)0.f;   // zero pad
  }
}

// ---------------------------------------------------------------------------
// MLP: user MLP via MFMA + final dot. 64 blocks x 16 users; weights from
// pre-swizzled frag tables (coalesced, L2-hot).
// ---------------------------------------------------------------------------
__global__ __launch_bounds__(256) void user_mlp_kernel(
    const int* __restrict__ target,
    const float* __restrict__ b_up1, const float* __restrict__ b_up2,
    const __bf16* __restrict__ Wup1f, const __bf16* __restrict__ Wup2f,
    const __bf16* __restrict__ Ucat, const float* __restrict__ T,
    float* __restrict__ out)
{
  __shared__ __align__(16) __bf16 s_u[16][UCS];   // 6.4 KB
  __shared__ __align__(16) __bf16 s_h[16][SH];    // 8.4 KB
  __shared__ __align__(16) float  s_e[16][132];   // 8.4 KB

  const int t = threadIdx.x, blk = blockIdx.x;
  const int wave = t >> 6, lane = t & 63, l15 = lane & 15, quad = lane >> 4;
  const int u0 = blk * 16;

  {  // stage Ucat tile: 16 thr/user, segs of 8 bf16 (24 segs of 16B)
    const int uu = t >> 4, s = t & 15;
    const __bf16* src = Ucat + (long)(u0 + uu) * UC;
    *(bf16x8*)&s_u[uu][s * 8] = *(const bf16x8*)(src + s * 8);
    if (s < 8)
      *(bf16x8*)&s_u[uu][(s + 16) * 8] = *(const bf16x8*)(src + (s + 16) * 8);
  }
  __syncthreads();

  // ---- up1: [16,192]@[192,256] -> relu -> s_h ----
  {
    bf16x8 af[KC_UP1];
    #pragma unroll
    for (int kc = 0; kc < KC_UP1; ++kc)
      af[kc] = *(const bf16x8*)&s_u[l15][kc * 32 + quad * 8];
    #pragma unroll
    for (int nt = 0; nt < 4; ++nt) {
      const int n = wave * 64 + nt * 16 + l15;
      const float bb = b_up1[n];
      f32x4 acc = {bb, bb, bb, bb};
      bf16x8 bfr[KC_UP1];
      #pragma unroll
      for (int kc = 0; kc < KC_UP1; ++kc)
        bfr[kc] = *(const bf16x8*)(Wup1f + ((long)(kc * NT_UP1 + wave * 4 + nt) * 64 + lane) * 8);
      #pragma unroll
      for (int kc = 0; kc < KC_UP1; ++kc)
        acc = mfma16(af[kc], bfr[kc], acc);
      #pragma unroll
      for (int r2 = 0; r2 < 4; ++r2)
        s_h[quad * 4 + r2][n] = (__bf16)fmaxf(acc[r2], 0.f);
    }
  }
  __syncthreads();

  // ---- up2: [16,256]@[256,128] -> s_e fp32 ----
  {
    bf16x8 af[KC_UP2];
    #pragma unroll
    for (int kc = 0; kc < KC_UP2; ++kc)
      af[kc] = *(const bf16x8*)&s_h[l15][kc * 32 + quad * 8];
    #pragma unroll
    for (int nt = 0; nt < 2; ++nt) {
      const int n = wave * 32 + nt * 16 + l15;
      const float bb = b_up2[n];
      f32x4 acc = {bb, bb, bb, bb};
      bf16x8 bfr[KC_UP2];
      #pragma unroll
      for (int kc = 0; kc < KC_UP2; ++kc)
        bfr[kc] = *(const bf16x8*)(Wup2f + ((long)(kc * NT_UP2 + wave * 2 + nt) * 64 + lane) * 8);
      #pragma unroll
      for (int kc = 0; kc < KC_UP2; ++kc)
        acc = mfma16(af[kc], bfr[kc], acc);
      #pragma unroll
      for (int r2 = 0; r2 < 4; ++r2)
        s_e[quad * 4 + r2][n] = acc[r2];
    }
  }
  __syncthreads();

  // ---- dot(user, T[target]): 8 threads per user ----
  if (t < 128) {
    const int uu = t >> 3, q = t & 7;
    const int tgt = target[u0 + uu];
    const float* trow = T + (long)tgt * OD + q * 16;
    float s = 0.f;
    #pragma unroll
    for (int i = 0; i < 4; ++i) {
      float4 v = *(const float4*)(trow + i * 4);
      f32x4 e = *(const f32x4*)&s_e[uu][q * 16 + i * 4];
      s += v.x * e[0] + v.y * e[1] + v.z * e[2] + v.w * e[3];
    }
    s += __shfl_down(s, 1, 64);
    s += __shfl_down(s, 2, 64);
    s += __shfl_down(s, 4, 64);
    if (q == 0) out[u0 + uu] = s;
  }
}

// ---------------------------------------------------------------------------
extern "C" void kernel_launch(void* const* d_in, const int* in_sizes, int n_in,
                              void* d_out, int out_size, void* d_ws, size_t ws_size,
                              hipStream_t stream) {
  const float* ugc      = (const float*)d_in[0];
  const int*   hist     = (const int*)  d_in[1];
  const float* ratings  = (const float*)d_in[2];
  const int*   tstamps  = (const int*)  d_in[3];
  const int*   target   = (const int*)  d_in[4];
  const float* genome   = (const float*)d_in[5];
  const float* genrec   = (const float*)d_in[6];
  const float* tagc     = (const float*)d_in[7];
  const int*   yearc    = (const int*)  d_in[8];
  const float* item_emb = (const float*)d_in[9];
  const float* year_tab = (const float*)d_in[10];
  const float* ts_tab   = (const float*)d_in[11];
  const float* w_item   = (const float*)d_in[12];
  const float* b_item   = (const float*)d_in[13];
  const float* w_genre  = (const float*)d_in[14];
  const float* b_genre  = (const float*)d_in[15];
  const float* w_tag    = (const float*)d_in[16];
  const float* b_tag    = (const float*)d_in[17];
  const float* w_genome = (const float*)d_in[18];
  const float* b_genome = (const float*)d_in[19];
  const float* w_year   = (const float*)d_in[20];
  const float* b_year   = (const float*)d_in[21];
  const float* w_ugenre = (const float*)d_in[22];
  const float* b_ugenre = (const float*)d_in[23];
  const float* w_ts     = (const float*)d_in[24];
  const float* b_ts     = (const float*)d_in[25];
  const float* w_up1    = (const float*)d_in[26];
  const float* b_up1    = (const float*)d_in[27];
  const float* w_up2    = (const float*)d_in[28];
  const float* b_up2    = (const float*)d_in[29];
  const float* w_ip1    = (const float*)d_in[30];
  const float* b_ip1    = (const float*)d_in[31];
  const float* w_ip2    = (const float*)d_in[32];
  const float* b_ip2    = (const float*)d_in[33];

  char* ws = (char*)d_ws;
  size_t off = 0;
  float*  T     = (float*) (ws + off); off += (size_t)PROWS * OD * 4;     // 10.25 MB
  float*  GT    = (float*) (ws + off); off += (size_t)PROWS * EGT * 4;    // 1.28 MB
  __bf16* Ucat  = (__bf16*)(ws + off); off += (size_t)NB * UC * 2;        // 0.39 MB
  __bf16* Wtf   = (__bf16*)(ws + off); off += (size_t)KC_TAG  * 512 * 2;
  __bf16* Wgf   = (__bf16*)(ws + off); off += (size_t)KC_GENF * 512 * 2;
  __bf16* Wip1f = (__bf16*)(ws + off); off += (size_t)KC_IP1 * NT_IP1 * 512 * 2;
  __bf16* Wip2f = (__bf16*)(ws + off); off += (size_t)KC_IP2 * NT_IP2 * 512 * 2;
  __bf16* Wup1f = (__bf16*)(ws + off); off += (size_t)KC_UP1 * NT_UP1 * 512 * 2;
  __bf16* Wup2f = (__bf16*)(ws + off); off += (size_t)KC_UP2 * NT_UP2 * 512 * 2;

  setup_wf_kernel<<<dim3(344), dim3(512), 0, stream>>>(
      w_tag, w_genome, w_ip1, w_ip2, w_up1, w_up2,
      Wtf, Wgf, Wip1f, Wip2f, Wup1f, Wup2f);

  tower_kernel<<<dim3(NT_TILE), dim3(256), 0, stream>>>(
      tagc, genome, genrec, yearc, item_emb, year_tab,
      w_genre, b_genre, b_tag, b_genome, w_item, b_item, w_year, b_year,
      b_ip1, b_ip2, Wtf, Wgf, Wip1f, Wip2f, T, GT);

  user_pool_kernel<<<dim3(NB), dim3(256), 0, stream>>>(
      ugc, hist, ratings, tstamps, ts_tab,
      w_ugenre, b_ugenre, w_ts, b_ts, T, GT, Ucat);

  user_mlp_kernel<<<dim3(NB / 16), dim3(256), 0, stream>>>(
      target, b_up1, b_up2, Wup1f, Wup2f, Ucat, T, (float*)d_out);
}

// Round 8
// 283.381 us; speedup vs baseline: 1.0421x; 1.0047x over previous
//
#include <hip/hip_runtime.h>
#include <hip/hip_bf16.h>

typedef __bf16 bf16x8 __attribute__((ext_vector_type(8)));
typedef __bf16 bf16x4 __attribute__((ext_vector_type(4)));
typedef float  f32x4  __attribute__((ext_vector_type(4)));

namespace {
constexpr int P       = 20001;   // MOVIES + 1 (padding row)
constexpr int NT_TILE = 1251;    // ceil(P/16) -> covers movies 0..20015
constexpr int PROWS   = NT_TILE * 16;  // 20016 padded rows for T/GT
constexpr int NGENRES = 20;
constexpr int NTAGS   = 1000;
constexpr int NGTAGS  = 1128;
constexpr int NB      = 1024;
constexpr int NH      = 50;
constexpr int PHID    = 256;
constexpr int OD      = 128;
constexpr int EG = 8, ET = 16, EGT = 16, EM = 32, EY = 8, EUG = 32, ETS = 4;
constexpr int PAD  = 20000;
constexpr int SC   = 104;    // s_cat stride bf16 (96 used)
constexpr int SH   = 264;    // hidden stride bf16 (256 used)
constexpr int UCS  = 200;    // user LDS stride for s_u tile (192 used)
// fragment-table chunk counts (chunks of K=32 -> one [64][8] bf16 frag = 1KB)
constexpr int KC_TAG  = 32;
constexpr int KC_GENF = 40;  // genome frags padded 36->40 (zeros): 2 halves x 20
constexpr int KC_IP1 = 3,  NT_IP1 = 16;   // K=96(80 real), N=256
constexpr int KC_IP2 = 8,  NT_IP2 = 8;    // K=256, N=128
constexpr int KC_UP1 = 6,  NT_UP1 = 16;   // K=192(180 real), N=256
constexpr int KC_UP2 = 8,  NT_UP2 = 8;    // K=256, N=128
}

static __device__ __forceinline__ f32x4 mfma16(bf16x8 a, bf16x8 b, f32x4 c) {
  return __builtin_amdgcn_mfma_f32_16x16x32_bf16(a, b, c, 0, 0, 0);
}

static __device__ __forceinline__ bf16x8 cvt8(float4 v0, float4 v1) {
  return (bf16x8){(__bf16)v0.x, (__bf16)v0.y, (__bf16)v0.z, (__bf16)v0.w,
                  (__bf16)v1.x, (__bf16)v1.y, (__bf16)v1.z, (__bf16)v1.w};
}

// async global->LDS DMA, 16B per lane, dest = wave-uniform base + lane*16
static __device__ __forceinline__ void gldlds(const void* g, void* l) {
  __builtin_amdgcn_global_load_lds(
      (const __attribute__((address_space(1))) void*)g,
      (__attribute__((address_space(3))) void*)l, 16, 0, 0);
}

// ---------------------------------------------------------------------------
// Setup: pre-swizzle all MFMA B-operands into fragment layout:
// frag(kc, nt)[lane][j] = W[kc*32 + (lane>>4)*8 + j][nt*16 + (lane&15)] (bf16,
// zero past K). One block (512 thr) per fragment; 344 fragments total.
// ---------------------------------------------------------------------------
__global__ __launch_bounds__(512) void setup_wf_kernel(
    const float* __restrict__ w_tag, const float* __restrict__ w_genome,
    const float* __restrict__ w_ip1, const float* __restrict__ w_ip2,
    const float* __restrict__ w_up1, const float* __restrict__ w_up2,
    __bf16* __restrict__ Wtf, __bf16* __restrict__ Wgf,
    __bf16* __restrict__ Wip1f, __bf16* __restrict__ Wip2f,
    __bf16* __restrict__ Wup1f, __bf16* __restrict__ Wup2f)
{
  const int b = blockIdx.x, t = threadIdx.x;
  const int l = t >> 3, j = t & 7;
  const int krow = (l >> 4) * 8 + j, l15 = l & 15;
  const float* src; __bf16* dst; int K, N, kc, nt;
  if (b < 32)        { src = w_tag;    dst = Wtf   + (long)b * 512;       K = NTAGS;  N = 16;  kc = b;      nt = 0; }
  else if (b < 72)   { int i = b - 32;  src = w_genome; dst = Wgf   + (long)i * 512; K = NGTAGS; N = 16;  kc = i;      nt = 0; }
  else if (b < 120)  { int i = b - 72;  src = w_ip1;    dst = Wip1f + (long)i * 512; K = 80;     N = 256; kc = i / 16; nt = i % 16; }
  else if (b < 184)  { int i = b - 120; src = w_ip2;    dst = Wip2f + (long)i * 512; K = 256;    N = 128; kc = i / 8;  nt = i % 8; }
  else if (b < 280)  { int i = b - 184; src = w_up1;    dst = Wup1f + (long)i * 512; K = 180;    N = 256; kc = i / 16; nt = i % 16; }
  else               { int i = b - 280; src = w_up2;    dst = Wup2f + (long)i * 512; K = 256;    N = 128; kc = i / 8;  nt = i % 8; }
  const int k = kc * 32 + krow, n = nt * 16 + l15;
  float v = (k < K) ? src[(long)k * N + n] : 0.f;
  dst[t] = (__bf16)v;
}

// ---------------------------------------------------------------------------
// Tower (R6 structure, verified-passing): one block = one 16-movie tile,
// 4 waves; row-contiguous global_load_lds staging through a 48KB union
// buffer, K in halves; XOR source-permute for conflict-free LDS A-reads.
// Pinned at ~82us by the combined L3+HBM delivery rate (~2.1 TB/s for this
// 155MB working set) -- invariant across 7 schedule variants.
// ---------------------------------------------------------------------------
__global__ __launch_bounds__(256, 2) void tower_kernel(
    const float* __restrict__ tag_ctx, const float* __restrict__ genome_ctx,
    const float* __restrict__ genre_ctx, const int* __restrict__ year_ctx,
    const float* __restrict__ item_emb, const float* __restrict__ year_tab,
    const float* __restrict__ w_genre, const float* __restrict__ b_genre,
    const float* __restrict__ b_tag,   const float* __restrict__ b_genome,
    const float* __restrict__ w_item,  const float* __restrict__ b_item,
    const float* __restrict__ w_year,  const float* __restrict__ b_year,
    const float* __restrict__ b_ip1,   const float* __restrict__ b_ip2,
    const __bf16* __restrict__ Wtf,   const __bf16* __restrict__ Wgf,
    const __bf16* __restrict__ Wip1f, const __bf16* __restrict__ Wip2f,
    float* __restrict__ T, float* __restrict__ GT)
{
  __shared__ __align__(16) union {
    char tag[16 * 128 * 16];   // 32 KB: [16 rows][128 float4 slots]
    char gen[16 * 192 * 16];   // 48 KB: [16 rows][192 slots] (160 used + pad)
  } u;
  __shared__ __align__(16) __bf16 s_cat[16][SC];   // 3.3 KB
  __shared__ __align__(16) __bf16 s_h[16][SH];     // 8.4 KB
  __shared__ __align__(16) f32x4  s_redT[3][64];   // 3 KB
  __shared__ __align__(16) f32x4  s_redG[3][64];   // 3 KB  -> total ~65.5 KB

  const int t = threadIdx.x, tile = blockIdx.x;
  const int wave = t >> 6, lane = t & 63, l15 = lane & 15, quad = lane >> 4;
  const int r = t >> 4, c16 = t & 15;               // small-tower coords
  const long rid_r = min(tile * 16 + r, P - 1);
  const int x = l15 & 7;                            // read-side XOR key

  f32x4 accT = {0.f, 0.f, 0.f, 0.f};
  f32x4 accG = {0.f, 0.f, 0.f, 0.f};

  // ===== tag: 2 halves of K (16 kc each) ====================================
  #pragma unroll
  for (int h = 0; h < 2; ++h) {
    #pragma unroll
    for (int cc = 0; cc < 8; ++cc) {
      const int c = wave * 8 + cc, rr = c >> 1, i = c & 1;
      const long rid = min(tile * 16 + rr, P - 1);
      const char* rp = (const char*)tag_ctx + rid * (NTAGS * 4);
      const int gs = min(((i * 64 + lane) ^ (rr & 7)) + h * 128, 249);
      gldlds(rp + (long)gs * 16, u.tag + ((rr * 128 + i * 64) * 16));
    }
    asm volatile("s_waitcnt vmcnt(0)" ::: "memory");
    __syncthreads();
    #pragma unroll
    for (int c = 0; c < 4; ++c) {                   // K-split: wave w kc w*4+c
      const int kcg = h * 16 + wave * 4 + c;
      const int j = (wave * 4 + c) * 8 + quad * 2;  // low3(j)=quad*2
      const float4* rowp = (const float4*)u.tag + l15 * 128;
      const float4 a0 = rowp[j ^ x];
      const float4 a1 = rowp[(j + 1) ^ x];
      bf16x8 tb = *(const bf16x8*)(Wtf + ((long)kcg * 64 + lane) * 8);
      accT = mfma16(cvt8(a0, a1), tb, accT);
    }
    __syncthreads();                                // before buffer reuse
  }

  // ===== genome: 2 halves of K (20 kc each; frags 36..39 zero) ==============
  #pragma unroll
  for (int h = 0; h < 2; ++h) {
    #pragma unroll
    for (int cc = 0; cc < 12; ++cc) {
      const int c = wave * 12 + cc, rr = c / 3, i = c % 3;
      const long rid = min(tile * 16 + rr, P - 1);
      const char* rp = (const char*)genome_ctx + rid * (NGTAGS * 4);
      const int gs = min(((i * 64 + lane) ^ (rr & 7)) + h * 160, 281);
      gldlds(rp + (long)gs * 16, u.gen + ((rr * 192 + i * 64) * 16));
    }
    asm volatile("s_waitcnt vmcnt(0)" ::: "memory");
    __syncthreads();
    #pragma unroll
    for (int c = 0; c < 5; ++c) {                   // K-split: wave w kc w*5+c
      const int kcg = h * 20 + wave * 5 + c;
      const int j = (wave * 5 + c) * 8 + quad * 2;  // < 160
      const float4* rowp = (const float4*)u.gen + l15 * 192;
      const float4 a0 = rowp[j ^ x];
      const float4 a1 = rowp[(j + 1) ^ x];
      bf16x8 gb = *(const bf16x8*)(Wgf + ((long)kcg * 64 + lane) * 8);
      accG = mfma16(cvt8(a0, a1), gb, accG);
    }
    __syncthreads();
  }

  if (wave > 0)  s_redT[wave - 1][lane] = accT;
  if (wave != 1) s_redG[wave ? wave - 1 : 0][lane] = accG;  // waves 0,2,3

  // ===== small towers (16 threads per movie: m = t>>4, j = t&15) ============
  {
    const int m = r, j = c16;
    const long id = rid_r;
    if (j < 8) {   // genre tower (8 cols)
      const float* rg = genre_ctx + id * NGENRES;
      float a = b_genre[j];
      #pragma unroll
      for (int k = 0; k < NGENRES; ++k) a = fmaf(rg[k], w_genre[k * EG + j], a);
      s_cat[m][j] = (__bf16)tanhf(a);
      s_cat[m][80 + j] = (__bf16)0.f;          // zero K-pad 80..95
      s_cat[m][88 + j] = (__bf16)0.f;
    } else {       // year tower (8 cols)
      const int jj = j - 8;
      const int yr = year_ctx[id];
      float a = b_year[jj];
      #pragma unroll
      for (int k = 0; k < EY; ++k)
        a = fmaf(year_tab[yr * EY + k], w_year[k * EY + jj], a);
      s_cat[m][72 + jj] = (__bf16)tanhf(a);    // 72 = EG+ET+EGT+EM
    }
    // item tower: every thread 2 cols
    const float* e = item_emb + id * EM;
    float a0 = b_item[2 * j], a1 = b_item[2 * j + 1];
    #pragma unroll 8
    for (int k = 0; k < EM; ++k) {
      float ev = e[k];
      a0 = fmaf(ev, w_item[k * EM + 2 * j], a0);
      a1 = fmaf(ev, w_item[k * EM + 2 * j + 1], a1);
    }
    s_cat[m][40 + 2 * j]     = (__bf16)tanhf(a0);   // 40 = EG+ET+EGT
    s_cat[m][40 + 2 * j + 1] = (__bf16)tanhf(a1);
  }
  __syncthreads();

  // ===== parallel epilogues: wave0 tag, wave1 genome ========================
  if (wave == 0) {
    accT += s_redT[0][lane]; accT += s_redT[1][lane]; accT += s_redT[2][lane];
    const float bt = b_tag[l15];
    #pragma unroll
    for (int r2 = 0; r2 < 4; ++r2)
      s_cat[quad * 4 + r2][EG + l15] = (__bf16)tanhf(accT[r2] + bt);
  } else if (wave == 1) {
    accG += s_redG[0][lane]; accG += s_redG[1][lane]; accG += s_redG[2][lane];
    const float bg = b_genome[l15];
    #pragma unroll
    for (int r2 = 0; r2 < 4; ++r2) {
      int m = quad * 4 + r2;
      float v = tanhf(accG[r2] + bg);
      s_cat[m][EG + ET + l15] = (__bf16)v;
      GT[(long)(tile * 16 + m) * EGT + l15] = v;
    }
  }
  __syncthreads();

  // ===== ip1 MFMA [16,96]@[96,256] -> relu -> s_h =====
  {
    bf16x8 af[KC_IP1];
    #pragma unroll
    for (int kc = 0; kc < KC_IP1; ++kc)
      af[kc] = *(const bf16x8*)&s_cat[l15][kc * 32 + quad * 8];
    #pragma unroll
    for (int nt = 0; nt < 4; ++nt) {
      const int n = wave * 64 + nt * 16 + l15;
      const float bb = b_ip1[n];
      f32x4 acc = {bb, bb, bb, bb};
      bf16x8 bfr[KC_IP1];
      #pragma unroll
      for (int kc = 0; kc < KC_IP1; ++kc)
        bfr[kc] = *(const bf16x8*)(Wip1f + ((long)(kc * NT_IP1 + wave * 4 + nt) * 64 + lane) * 8);
      #pragma unroll
      for (int kc = 0; kc < KC_IP1; ++kc)
        acc = mfma16(af[kc], bfr[kc], acc);
      #pragma unroll
      for (int r2 = 0; r2 < 4; ++r2)
        s_h[quad * 4 + r2][n] = (__bf16)fmaxf(acc[r2], 0.f);
    }
  }
  __syncthreads();

  // ===== ip2 MFMA [16,256]@[256,128] -> T =====
  {
    bf16x8 af[KC_IP2];
    #pragma unroll
    for (int kc = 0; kc < KC_IP2; ++kc)
      af[kc] = *(const bf16x8*)&s_h[l15][kc * 32 + quad * 8];
    #pragma unroll
    for (int nt = 0; nt < 2; ++nt) {
      const int n = wave * 32 + nt * 16 + l15;
      const float bb = b_ip2[n];
      f32x4 acc = {bb, bb, bb, bb};
      bf16x8 bfr[KC_IP2];
      #pragma unroll
      for (int kc = 0; kc < KC_IP2; ++kc)
        bfr[kc] = *(const bf16x8*)(Wip2f + ((long)(kc * NT_IP2 + wave * 2 + nt) * 64 + lane) * 8);
      #pragma unroll
      for (int kc = 0; kc < KC_IP2; ++kc)
        acc = mfma16(af[kc], bfr[kc], acc);
      #pragma unroll
      for (int r2 = 0; r2 < 4; ++r2)
        T[(long)(tile * 16 + quad * 4 + r2) * OD + n] = acc[r2];
    }
  }
}

// ---------------------------------------------------------------------------
// Fused user kernel: pooling + user MLP + final dot in ONE kernel.
// 64 blocks x 256 thr, 16 users per block; 16 threads per user (q = t&15).
// Removes the user_pool launch, the Ucat global round-trip, and one sync
// boundary. Pool sums go straight into the s_u LDS tile (bf16, same values
// the old Ucat path produced), then up1/up2/dot run unchanged.
// ---------------------------------------------------------------------------
__global__ __launch_bounds__(256) void user_kernel(
    const float* __restrict__ ugc, const int* __restrict__ hist,
    const float* __restrict__ ratings, const int* __restrict__ tstamps,
    const float* __restrict__ ts_tab,
    const float* __restrict__ w_ugenre, const float* __restrict__ b_ugenre,
    const float* __restrict__ w_ts, const float* __restrict__ b_ts,
    const int* __restrict__ target,
    const float* __restrict__ b_up1, const float* __restrict__ b_up2,
    const __bf16* __restrict__ Wup1f, const __bf16* __restrict__ Wup2f,
    const float* __restrict__ T, const float* __restrict__ GT,
    float* __restrict__ out)
{
  __shared__ __align__(16) __bf16 s_u[16][UCS];   // 6.4 KB
  __shared__ __align__(16) __bf16 s_h[16][SH];    // 8.4 KB
  __shared__ __align__(16) float  s_e[16][132];   // 8.4 KB
  __shared__ float s_w[16][NH + 2];
  __shared__ int   s_ids[16][NH + 2];
  __shared__ float s_inv[16];

  const int t = threadIdx.x, blk = blockIdx.x;
  const int wave = t >> 6, lane = t & 63, l15 = lane & 15, quad = lane >> 4;
  const int u0 = blk * 16;
  const int uu = t >> 4, q = t & 15;              // user-slot coords

  // ---- phase 0: history weights + |w| sum (16 thr per user) ----
  {
    float psum = 0.f;
    for (int i = q; i < NH; i += 16) {
      const int id = hist[(long)(u0 + uu) * NH + i];
      const float rr = ratings[(long)(u0 + uu) * NH + i];
      const float w = (id != PAD) ? rr : 0.f;
      s_ids[uu][i] = id; s_w[uu][i] = w;
      psum += fabsf(w);
    }
    psum += __shfl_xor(psum, 1, 64);
    psum += __shfl_xor(psum, 2, 64);
    psum += __shfl_xor(psum, 4, 64);
    psum += __shfl_xor(psum, 8, 64);
    if (q == 0) s_inv[uu] = 1.f / fmaxf(psum, 1e-6f);
  }
  __syncthreads();

  // ---- phase 1+2: item pool (8 T-cols/thread) + genome pool (1 GT-col) ----
  {
    const float inv = s_inv[uu];
    const int c0 = q * 8;
    float acc[8] = {0.f, 0.f, 0.f, 0.f, 0.f, 0.f, 0.f, 0.f};
    float gacc = 0.f;
    for (int h = 0; h < NH; ++h) {
      const int id = s_ids[uu][h];
      const float w = s_w[uu][h];
      const float* trow = T + (long)id * OD + c0;
      const float4 v0 = *(const float4*)trow;
      const float4 v1 = *(const float4*)(trow + 4);
      acc[0] = fmaf(w, v0.x, acc[0]); acc[1] = fmaf(w, v0.y, acc[1]);
      acc[2] = fmaf(w, v0.z, acc[2]); acc[3] = fmaf(w, v0.w, acc[3]);
      acc[4] = fmaf(w, v1.x, acc[4]); acc[5] = fmaf(w, v1.y, acc[5]);
      acc[6] = fmaf(w, v1.z, acc[6]); acc[7] = fmaf(w, v1.w, acc[7]);
      gacc = fmaf(w, GT[(long)id * EGT + q], gacc);
    }
    #pragma unroll
    for (int j = 0; j < 8; ++j) s_u[uu][c0 + j] = (__bf16)(acc[j] * inv);
    s_u[uu][OD + q] = (__bf16)(gacc * inv);
  }

  // ---- phase 3: ugenre tower (2 cols/thread) ----
  {
    const float* ug = ugc + (long)(u0 + uu) * NGENRES;
    #pragma unroll
    for (int jj = 0; jj < 2; ++jj) {
      const int j = q * 2 + jj;
      float a = b_ugenre[j];
      #pragma unroll
      for (int k = 0; k < NGENRES; ++k)
        a = fmaf(ug[k], w_ugenre[k * EUG + j], a);
      s_u[uu][144 + j] = (__bf16)tanhf(a);       // 128 + 16
    }
  }
  // ---- phase 4: ts tower (q<4) + zero pad (q>=4 -> 180..191) ----
  if (q < ETS) {
    const int ts = tstamps[u0 + uu];
    float a = b_ts[q];
    #pragma unroll
    for (int k = 0; k < ETS; ++k)
      a = fmaf(ts_tab[ts * ETS + k], w_ts[k * ETS + q], a);
    s_u[uu][176 + q] = (__bf16)tanhf(a);         // 128 + 16 + 32
  } else {
    s_u[uu][176 + q] = (__bf16)0.f;              // 180..191 zero pad
  }
  __syncthreads();

  // ---- up1: [16,192]@[192,256] -> relu -> s_h ----
  {
    bf16x8 af[KC_UP1];
    #pragma unroll
    for (int kc = 0; kc < KC_UP1; ++kc)
      af[kc] = *(const bf16x8*)&s_u[l15][kc * 32 + quad * 8];
    #pragma unroll
    for (int nt = 0; nt < 4; ++nt) {
      const int n = wave * 64 + nt * 16 + l15;
      const float bb = b_up1[n];
      f32x4 acc = {bb, bb, bb, bb};
      bf16x8 bfr[KC_UP1];
      #pragma unroll
      for (int kc = 0; kc < KC_UP1; ++kc)
        bfr[kc] = *(const bf16x8*)(Wup1f + ((long)(kc * NT_UP1 + wave * 4 + nt) * 64 + lane) * 8);
      #pragma unroll
      for (int kc = 0; kc < KC_UP1; ++kc)
        acc = mfma16(af[kc], bfr[kc], acc);
      #pragma unroll
      for (int r2 = 0; r2 < 4; ++r2)
        s_h[quad * 4 + r2][n] = (__bf16)fmaxf(acc[r2], 0.f);
    }
  }
  __syncthreads();

  // ---- up2: [16,256]@[256,128] -> s_e fp32 ----
  {
    bf16x8 af[KC_UP2];
    #pragma unroll
    for (int kc = 0; kc < KC_UP2; ++kc)
      af[kc] = *(const bf16x8*)&s_h[l15][kc * 32 + quad * 8];
    #pragma unroll
    for (int nt = 0; nt < 2; ++nt) {
      const int n = wave * 32 + nt * 16 + l15;
      const float bb = b_up2[n];
      f32x4 acc = {bb, bb, bb, bb};
      bf16x8 bfr[KC_UP2];
      #pragma unroll
      for (int kc = 0; kc < KC_UP2; ++kc)
        bfr[kc] = *(const bf16x8*)(Wup2f + ((long)(kc * NT_UP2 + wave * 2 + nt) * 64 + lane) * 8);
      #pragma unroll
      for (int kc = 0; kc < KC_UP2; ++kc)
        acc = mfma16(af[kc], bfr[kc], acc);
      #pragma unroll
      for (int r2 = 0; r2 < 4; ++r2)
        s_e[quad * 4 + r2][n] = acc[r2];
    }
  }
  __syncthreads();

  // ---- dot(user, T[target]): 8 threads per user ----
  if (t < 128) {
    const int us = t >> 3, q8 = t & 7;
    const int tgt = target[u0 + us];
    const float* trow = T + (long)tgt * OD + q8 * 16;
    float s = 0.f;
    #pragma unroll
    for (int i = 0; i < 4; ++i) {
      float4 v = *(const float4*)(trow + i * 4);
      f32x4 e = *(const f32x4*)&s_e[us][q8 * 16 + i * 4];
      s += v.x * e[0] + v.y * e[1] + v.z * e[2] + v.w * e[3];
    }
    s += __shfl_down(s, 1, 64);
    s += __shfl_down(s, 2, 64);
    s += __shfl_down(s, 4, 64);
    if (q8 == 0) out[u0 + us] = s;
  }
}

// ---------------------------------------------------------------------------
extern "C" void kernel_launch(void* const* d_in, const int* in_sizes, int n_in,
                              void* d_out, int out_size, void* d_ws, size_t ws_size,
                              hipStream_t stream) {
  const float* ugc      = (const float*)d_in[0];
  const int*   hist     = (const int*)  d_in[1];
  const float* ratings  = (const float*)d_in[2];
  const int*   tstamps  = (const int*)  d_in[3];
  const int*   target   = (const int*)  d_in[4];
  const float* genome   = (const float*)d_in[5];
  const float* genrec   = (const float*)d_in[6];
  const float* tagc     = (const float*)d_in[7];
  const int*   yearc    = (const int*)  d_in[8];
  const float* item_emb = (const float*)d_in[9];
  const float* year_tab = (const float*)d_in[10];
  const float* ts_tab   = (const float*)d_in[11];
  const float* w_item   = (const float*)d_in[12];
  const float* b_item   = (const float*)d_in[13];
  const float* w_genre  = (const float*)d_in[14];
  const float* b_genre  = (const float*)d_in[15];
  const float* w_tag    = (const float*)d_in[16];
  const float* b_tag    = (const float*)d_in[17];
  const float* w_genome = (const float*)d_in[18];
  const float* b_genome = (const float*)d_in[19];
  const float* w_year   = (const float*)d_in[20];
  const float* b_year   = (const float*)d_in[21];
  const float* w_ugenre = (const float*)d_in[22];
  const float* b_ugenre = (const float*)d_in[23];
  const float* w_ts     = (const float*)d_in[24];
  const float* b_ts     = (const float*)d_in[25];
  const float* w_up1    = (const float*)d_in[26];
  const float* b_up1    = (const float*)d_in[27];
  const float* w_up2    = (const float*)d_in[28];
  const float* b_up2    = (const float*)d_in[29];
  const float* w_ip1    = (const float*)d_in[30];
  const float* b_ip1    = (const float*)d_in[31];
  const float* w_ip2    = (const float*)d_in[32];
  const float* b_ip2    = (const float*)d_in[33];

  char* ws = (char*)d_ws;
  size_t off = 0;
  float*  T     = (float*) (ws + off); off += (size_t)PROWS * OD * 4;      // 10.25 MB
  float*  GT    = (float*) (ws + off); off += (size_t)PROWS * EGT * 4;     // 1.28 MB
  __bf16* Wtf   = (__bf16*)(ws + off); off += (size_t)KC_TAG  * 512 * 2;
  __bf16* Wgf   = (__bf16*)(ws + off); off += (size_t)KC_GENF * 512 * 2;
  __bf16* Wip1f = (__bf16*)(ws + off); off += (size_t)KC_IP1 * NT_IP1 * 512 * 2;
  __bf16* Wip2f = (__bf16*)(ws + off); off += (size_t)KC_IP2 * NT_IP2 * 512 * 2;
  __bf16* Wup1f = (__bf16*)(ws + off); off += (size_t)KC_UP1 * NT_UP1 * 512 * 2;
  __bf16* Wup2f = (__bf16*)(ws + off); off += (size_t)KC_UP2 * NT_UP2 * 512 * 2;

  setup_wf_kernel<<<dim3(344), dim3(512), 0, stream>>>(
      w_tag, w_genome, w_ip1, w_ip2, w_up1, w_up2,
      Wtf, Wgf, Wip1f, Wip2f, Wup1f, Wup2f);

  tower_kernel<<<dim3(NT_TILE), dim3(256), 0, stream>>>(
      tagc, genome, genrec, yearc, item_emb, year_tab,
      w_genre, b_genre, b_tag, b_genome, w_item, b_item, w_year, b_year,
      b_ip1, b_ip2, Wtf, Wgf, Wip1f, Wip2f, T, GT);

  user_kernel<<<dim3(NB / 16), dim3(256), 0, stream>>>(
      ugc, hist, ratings, tstamps, ts_tab,
      w_ugenre, b_ugenre, w_ts, b_ts,
      target, b_up1, b_up2, Wup1f, Wup2f, T, GT, (float*)d_out);
}